// Round 9
// baseline (279.551 us; speedup 1.0000x reference)
//
#include <hip/hip_runtime.h>
#include <hip/hip_fp16.h>

// Cone-beam backprojection, TIGRE-style geometry.
// sinogram: [B=1, C=8, A=120, V=128, U=128] f32
// angles:   [A=120] f32
// out:      [B=1, C=8, NZ=96, NY=96, NX=96] f32
//
// v6: v5 inner loop (f16 [A][V][U][C] records, clamp-126 single-base corner
// loads, __hfma2 chunk accumulation) + angle-split across lane pairs:
// lanes (2s, 2s+1) handle the same (x,y,z-pair) voxels for angles [0,60) and
// [60,120) respectively; partners combine via __shfl_xor at the end. Doubles
// resident waves (3456 blocks) at ~zero instruction overhead. Fast rcp for mag.

#define A_N   120
#define V_N   128
#define U_N   128
#define NZv   96
#define NYv   96
#define NXv   96
#define C_N   8
#define ZPT   2                          // z per thread
#define AHALF (A_N / 2)                  // 60 angles per lane of a pair

constexpr float DSO  = 1000.0f;
constexpr float DSD  = 1500.0f;
constexpr float DVOX = 0.8f;

#define NVOX   (NZv * NYv * NXv)        // 884736
#define SINO_N (A_N * V_N * U_N)        // 1966080 per channel
#define CHUNK  10                        // angles per f16-accum chunk

struct alignas(16) H8 { __half2 h[4]; };  // 8 channels = 16 B record

// ---------------------------------------------------------------------------
// Pre-pass: [C, A, V, U] f32 -> [A, V, U, C] f16 (one 16B record per (a,v,u))
// ---------------------------------------------------------------------------
__global__ __launch_bounds__(256) void sino_to_h(
    const float* __restrict__ in, H8* __restrict__ out) {
  int idx = blockIdx.x * 256 + threadIdx.x;   // over A*V*U, exact grid
  H8 o;
#pragma unroll
  for (int i = 0; i < 4; ++i) {
    float lo = in[(size_t)(2 * i)     * SINO_N + idx];
    float hi = in[(size_t)(2 * i + 1) * SINO_N + idx];
    o.h[i] = __floats2half2_rn(lo, hi);
  }
  out[idx] = o;
}

// ---------------------------------------------------------------------------
// Backprojection: lane-pair angle split, z-pair per lane, f16 chunk accum
// ---------------------------------------------------------------------------
__global__ __launch_bounds__(256) void backproject_p(
    const H8* __restrict__ sino,
    const float* __restrict__ angles,
    float* __restrict__ out) {
  __shared__ float s_c[A_N];
  __shared__ float s_s[A_N];
  int tid = threadIdx.x;
  if (tid < A_N) {
    float a = angles[tid];
    s_c[tid] = cosf(a);
    s_s[tid] = sinf(a);
  }
  __syncthreads();

  int g     = blockIdx.x * 256 + tid;       // over NVOX (pairs x2), exact grid
  int ah    = g & 1;                         // angle half: 0 -> [0,60), 1 -> [60,120)
  int s     = g >> 1;                        // spatial index over NVOX/ZPT
  int abase = ah * AHALF;

  int x  = s % NXv;
  int r  = s / NXv;
  int y  = r % NYv;
  int z0 = (r / NYv) * ZPT;

  float xf = ((float)x - (NXv - 1) * 0.5f) * DVOX;
  float yf = ((float)y - (NYv - 1) * 0.5f) * DVOX;
  float zf[ZPT];
#pragma unroll
  for (int k = 0; k < ZPT; ++k)
    zf[k] = ((float)(z0 + k) - (NZv - 1) * 0.5f) * DVOX;

  float2  accf[ZPT][4];                      // f32 master accumulators
  __half2 acch[ZPT][4];                      // f16 chunk accumulators
#pragma unroll
  for (int k = 0; k < ZPT; ++k)
#pragma unroll
    for (int i = 0; i < 4; ++i) {
      accf[k][i] = make_float2(0.0f, 0.0f);
      acch[k][i] = __float2half2_rn(0.0f);
    }

  for (int chnk = 0; chnk < AHALF / CHUNK; ++chnk) {
#pragma unroll 2
    for (int j = 0; j < CHUNK; ++j) {
      int a = abase + chnk * CHUNK + j;
      float cs = s_c[a], sn = s_s[a];
      float xr  = xf * cs + yf * sn;
      float yr  = yf * cs - xf * sn;
      float mag = DSD * __builtin_amdgcn_rcpf(DSO - xr);  // fast rcp, ~1e-6 rel
      float w   = mag * mag;

      // u-interp setup shared by both z (clamp-126: u1 = u0+1 always)
      float iu  = yr * mag + (U_N - 1) * 0.5f;
      bool uok  = (iu >= 0.0f) && (iu <= (float)(U_N - 1));
      float iuc = fminf(fmaxf(iu, 0.0f), (float)(U_N - 1));
      float u0f = fminf(floorf(iuc), (float)(U_N - 2));
      float fu  = iuc - u0f;                 // in [0,1]
      float gu  = 1.0f - fu;
      int u0    = (int)u0f;
      float wu  = uok ? w : 0.0f;
      const H8* arow = sino + (size_t)(a * (V_N * U_N) + u0);

#pragma unroll
      for (int k = 0; k < ZPT; ++k) {
        float iv  = fmaf(zf[k], mag, (V_N - 1) * 0.5f);
        bool ok   = (iv >= 0.0f) && (iv <= (float)(V_N - 1));
        float ivc = fminf(fmaxf(iv, 0.0f), (float)(V_N - 1));
        float v0f = fminf(floorf(ivc), (float)(V_N - 2));
        float fv  = ivc - v0f;
        int v0    = (int)v0f;
        float wz  = ok ? wu : 0.0f;
        float wv0 = wz * (1.0f - fv);
        float wv1 = wz * fv;

        __half2 h00 = __float2half2_rn(wv0 * gu);
        __half2 h01 = __float2half2_rn(wv0 * fu);
        __half2 h10 = __float2half2_rn(wv1 * gu);
        __half2 h11 = __float2half2_rn(wv1 * fu);

        const H8* p = arow + v0 * U_N;       // imm offsets 0,16,2048,2064
        H8 c00 = p[0];
        H8 c01 = p[1];
        H8 c10 = p[U_N];
        H8 c11 = p[U_N + 1];

#pragma unroll
        for (int i = 0; i < 4; ++i) {
          acch[k][i] = __hfma2(c00.h[i], h00,
                       __hfma2(c01.h[i], h01,
                       __hfma2(c10.h[i], h10,
                       __hfma2(c11.h[i], h11, acch[k][i]))));
        }
      }
    }
    // flush f16 chunk into f32 master accumulators
#pragma unroll
    for (int k = 0; k < ZPT; ++k)
#pragma unroll
      for (int i = 0; i < 4; ++i) {
        float2 sf = __half22float2(acch[k][i]);
        accf[k][i].x += sf.x;
        accf[k][i].y += sf.y;
        acch[k][i] = __float2half2_rn(0.0f);
      }
  }

  // Combine lane pairs (2s, 2s+1): both halves of the angle sum.
#pragma unroll
  for (int k = 0; k < ZPT; ++k)
#pragma unroll
    for (int i = 0; i < 4; ++i) {
      accf[k][i].x += __shfl_xor(accf[k][i].x, 1);
      accf[k][i].y += __shfl_xor(accf[k][i].y, 1);
    }

  if (ah == 0) {
#pragma unroll
    for (int k = 0; k < ZPT; ++k) {
      int vi = ((z0 + k) * NYv + y) * NXv + x;
#pragma unroll
      for (int i = 0; i < 4; ++i) {
        out[(size_t)(2 * i)     * NVOX + vi] = accf[k][i].x;
        out[(size_t)(2 * i + 1) * NVOX + vi] = accf[k][i].y;
      }
    }
  }
}

// ---------------------------------------------------------------------------
// Fallback: direct [C][A][V][U] f32 layout (if workspace too small)
// ---------------------------------------------------------------------------
__global__ __launch_bounds__(256) void backproject_direct(
    const float* __restrict__ sino,
    const float* __restrict__ angles,
    float* __restrict__ out) {
  __shared__ float s_c[A_N];
  __shared__ float s_s[A_N];
  int tid = threadIdx.x;
  if (tid < A_N) {
    float a = angles[tid];
    s_c[tid] = cosf(a);
    s_s[tid] = sinf(a);
  }
  __syncthreads();

  int vi = blockIdx.x * 256 + tid;
  int x = vi % NXv;
  int t = vi / NXv;
  int y = t % NYv;
  int z = t / NYv;

  float xf = ((float)x - (NXv - 1) * 0.5f) * DVOX;
  float yf = ((float)y - (NYv - 1) * 0.5f) * DVOX;
  float zf = ((float)z - (NZv - 1) * 0.5f) * DVOX;

  float acc[C_N];
#pragma unroll
  for (int c = 0; c < C_N; ++c) acc[c] = 0.0f;

  for (int a = 0; a < A_N; ++a) {
    float cs = s_c[a], sn = s_s[a];
    float xr = xf * cs + yf * sn;
    float yr = yf * cs - xf * sn;
    float mag = DSD / (DSO - xr);
    float iu = yr * mag + (U_N - 1) * 0.5f;
    float iv = zf * mag + (V_N - 1) * 0.5f;
    if (iu < 0.0f || iu > (float)(U_N - 1) || iv < 0.0f || iv > (float)(V_N - 1))
      continue;
    float u0f = floorf(iu), v0f = floorf(iv);
    float fu = iu - u0f, fv = iv - v0f;
    int u0 = (int)u0f, v0 = (int)v0f;
    int u1 = min(u0 + 1, U_N - 1);
    int v1 = min(v0 + 1, V_N - 1);
    float w = mag * mag;
    float w00 = w * (1.0f - fv) * (1.0f - fu);
    float w01 = w * (1.0f - fv) * fu;
    float w10 = w * fv * (1.0f - fu);
    float w11 = w * fv * fu;

    int b00 = (a * V_N + v0) * U_N + u0;
    int b01 = (a * V_N + v0) * U_N + u1;
    int b10 = (a * V_N + v1) * U_N + u0;
    int b11 = (a * V_N + v1) * U_N + u1;
#pragma unroll
    for (int c = 0; c < C_N; ++c) {
      const float* pc = sino + (size_t)c * SINO_N;
      acc[c] += w00 * pc[b00] + w01 * pc[b01] + w10 * pc[b10] + w11 * pc[b11];
    }
  }

#pragma unroll
  for (int c = 0; c < C_N; ++c)
    out[(size_t)c * NVOX + vi] = acc[c];
}

extern "C" void kernel_launch(void* const* d_in, const int* in_sizes, int n_in,
                              void* d_out, int out_size, void* d_ws, size_t ws_size,
                              hipStream_t stream) {
  const float* sino   = (const float*)d_in[0];
  const float* angles = (const float*)d_in[1];
  float* out = (float*)d_out;

  size_t need = (size_t)SINO_N * sizeof(H8);   // 31.5 MB
  if (ws_size >= need) {
    H8* sino_h = (H8*)d_ws;
    sino_to_h<<<SINO_N / 256, 256, 0, stream>>>(sino, sino_h);
    backproject_p<<<NVOX / 256, 256, 0, stream>>>(sino_h, angles, out);
  } else {
    backproject_direct<<<NVOX / 256, 256, 0, stream>>>(sino, angles, out);
  }
}

// Round 10
// 234.796 us; speedup vs baseline: 1.1906x; 1.1906x over previous
//
#include <hip/hip_runtime.h>
#include <hip/hip_fp16.h>

// Cone-beam backprojection, TIGRE-style geometry.
// sinogram: [B=1, C=8, A=120, V=128, U=128] f32
// angles:   [A=120] f32
// out:      [B=1, C=8, NZ=96, NY=96, NX=96] f32
//
// v7: v5 structure (f16 [A][V][U][C] records, clamp-126 single-base corner
// loads, __hfma2 chunk accumulation, ZPT=2, 1728 blocks — wave-coherent
// single-slab access) + ILP: angle loop unrolled 4x (consecutive angles are
// independent; keeps one slab window per wave, unlike v6's lane split) and
// fast v_rcp_f32 for the magnification divide.

#define A_N   120
#define V_N   128
#define U_N   128
#define NZv   96
#define NYv   96
#define NXv   96
#define C_N   8
#define ZPT   2                          // z per thread

constexpr float DSO  = 1000.0f;
constexpr float DSD  = 1500.0f;
constexpr float DVOX = 0.8f;

#define NVOX   (NZv * NYv * NXv)        // 884736
#define SINO_N (A_N * V_N * U_N)        // 1966080 per channel
#define CHUNK  12                        // angles per f16-accum chunk (10 flushes)

struct alignas(16) H8 { __half2 h[4]; };  // 8 channels = 16 B record

// ---------------------------------------------------------------------------
// Pre-pass: [C, A, V, U] f32 -> [A, V, U, C] f16 (one 16B record per (a,v,u))
// ---------------------------------------------------------------------------
__global__ __launch_bounds__(256) void sino_to_h(
    const float* __restrict__ in, H8* __restrict__ out) {
  int idx = blockIdx.x * 256 + threadIdx.x;   // over A*V*U, exact grid
  H8 o;
#pragma unroll
  for (int i = 0; i < 4; ++i) {
    float lo = in[(size_t)(2 * i)     * SINO_N + idx];
    float hi = in[(size_t)(2 * i + 1) * SINO_N + idx];
    o.h[i] = __floats2half2_rn(lo, hi);
  }
  out[idx] = o;
}

// ---------------------------------------------------------------------------
// Backprojection: f16 records, z-pair per thread, 4x-unrolled angle loop
// ---------------------------------------------------------------------------
__global__ __launch_bounds__(256) void backproject_u4(
    const H8* __restrict__ sino,
    const float* __restrict__ angles,
    float* __restrict__ out) {
  __shared__ float s_c[A_N];
  __shared__ float s_s[A_N];
  int tid = threadIdx.x;
  if (tid < A_N) {
    float a = angles[tid];
    s_c[tid] = cosf(a);
    s_s[tid] = sinf(a);
  }
  __syncthreads();

  int t  = blockIdx.x * 256 + tid;            // over NVOX/ZPT, exact grid
  int x  = t % NXv;
  int r  = t / NXv;
  int y  = r % NYv;
  int z0 = (r / NYv) * ZPT;

  float xf = ((float)x - (NXv - 1) * 0.5f) * DVOX;
  float yf = ((float)y - (NYv - 1) * 0.5f) * DVOX;
  float zf[ZPT];
#pragma unroll
  for (int k = 0; k < ZPT; ++k)
    zf[k] = ((float)(z0 + k) - (NZv - 1) * 0.5f) * DVOX;

  float2  accf[ZPT][4];                       // f32 master accumulators
  __half2 acch[ZPT][4];                       // f16 chunk accumulators
#pragma unroll
  for (int k = 0; k < ZPT; ++k)
#pragma unroll
    for (int i = 0; i < 4; ++i) {
      accf[k][i] = make_float2(0.0f, 0.0f);
      acch[k][i] = __float2half2_rn(0.0f);
    }

  for (int chnk = 0; chnk < A_N / CHUNK; ++chnk) {
#pragma unroll 4
    for (int j = 0; j < CHUNK; ++j) {
      int a = chnk * CHUNK + j;
      float cs = s_c[a], sn = s_s[a];
      float xr  = xf * cs + yf * sn;
      float yr  = yf * cs - xf * sn;
      float mag = DSD * __builtin_amdgcn_rcpf(DSO - xr);  // fast rcp, ~1e-6 rel
      float w   = mag * mag;

      // u-interp setup shared by both z (clamp-126: u1 = u0+1 always)
      float iu  = yr * mag + (U_N - 1) * 0.5f;
      bool uok  = (iu >= 0.0f) && (iu <= (float)(U_N - 1));
      float iuc = fminf(fmaxf(iu, 0.0f), (float)(U_N - 1));
      float u0f = fminf(floorf(iuc), (float)(U_N - 2));
      float fu  = iuc - u0f;                  // in [0,1]
      float gu  = 1.0f - fu;
      int u0    = (int)u0f;
      float wu  = uok ? w : 0.0f;
      const H8* arow = sino + (size_t)(a * (V_N * U_N) + u0);

#pragma unroll
      for (int k = 0; k < ZPT; ++k) {
        float iv  = fmaf(zf[k], mag, (V_N - 1) * 0.5f);
        bool ok   = (iv >= 0.0f) && (iv <= (float)(V_N - 1));
        float ivc = fminf(fmaxf(iv, 0.0f), (float)(V_N - 1));
        float v0f = fminf(floorf(ivc), (float)(V_N - 2));
        float fv  = ivc - v0f;
        int v0    = (int)v0f;
        float wz  = ok ? wu : 0.0f;
        float wv0 = wz * (1.0f - fv);
        float wv1 = wz * fv;

        __half2 h00 = __float2half2_rn(wv0 * gu);
        __half2 h01 = __float2half2_rn(wv0 * fu);
        __half2 h10 = __float2half2_rn(wv1 * gu);
        __half2 h11 = __float2half2_rn(wv1 * fu);

        const H8* p = arow + v0 * U_N;        // imm offsets 0,16,2048,2064
        H8 c00 = p[0];
        H8 c01 = p[1];
        H8 c10 = p[U_N];
        H8 c11 = p[U_N + 1];

#pragma unroll
        for (int i = 0; i < 4; ++i) {
          acch[k][i] = __hfma2(c00.h[i], h00,
                       __hfma2(c01.h[i], h01,
                       __hfma2(c10.h[i], h10,
                       __hfma2(c11.h[i], h11, acch[k][i]))));
        }
      }
    }
    // flush f16 chunk into f32 master accumulators
#pragma unroll
    for (int k = 0; k < ZPT; ++k)
#pragma unroll
      for (int i = 0; i < 4; ++i) {
        float2 sf = __half22float2(acch[k][i]);
        accf[k][i].x += sf.x;
        accf[k][i].y += sf.y;
        acch[k][i] = __float2half2_rn(0.0f);
      }
  }

#pragma unroll
  for (int k = 0; k < ZPT; ++k) {
    int vi = ((z0 + k) * NYv + y) * NXv + x;
#pragma unroll
    for (int i = 0; i < 4; ++i) {
      out[(size_t)(2 * i)     * NVOX + vi] = accf[k][i].x;
      out[(size_t)(2 * i + 1) * NVOX + vi] = accf[k][i].y;
    }
  }
}

// ---------------------------------------------------------------------------
// Fallback: direct [C][A][V][U] f32 layout (if workspace too small)
// ---------------------------------------------------------------------------
__global__ __launch_bounds__(256) void backproject_direct(
    const float* __restrict__ sino,
    const float* __restrict__ angles,
    float* __restrict__ out) {
  __shared__ float s_c[A_N];
  __shared__ float s_s[A_N];
  int tid = threadIdx.x;
  if (tid < A_N) {
    float a = angles[tid];
    s_c[tid] = cosf(a);
    s_s[tid] = sinf(a);
  }
  __syncthreads();

  int vi = blockIdx.x * 256 + tid;
  int x = vi % NXv;
  int t = vi / NXv;
  int y = t % NYv;
  int z = t / NYv;

  float xf = ((float)x - (NXv - 1) * 0.5f) * DVOX;
  float yf = ((float)y - (NYv - 1) * 0.5f) * DVOX;
  float zf = ((float)z - (NZv - 1) * 0.5f) * DVOX;

  float acc[C_N];
#pragma unroll
  for (int c = 0; c < C_N; ++c) acc[c] = 0.0f;

  for (int a = 0; a < A_N; ++a) {
    float cs = s_c[a], sn = s_s[a];
    float xr = xf * cs + yf * sn;
    float yr = yf * cs - xf * sn;
    float mag = DSD / (DSO - xr);
    float iu = yr * mag + (U_N - 1) * 0.5f;
    float iv = zf * mag + (V_N - 1) * 0.5f;
    if (iu < 0.0f || iu > (float)(U_N - 1) || iv < 0.0f || iv > (float)(V_N - 1))
      continue;
    float u0f = floorf(iu), v0f = floorf(iv);
    float fu = iu - u0f, fv = iv - v0f;
    int u0 = (int)u0f, v0 = (int)v0f;
    int u1 = min(u0 + 1, U_N - 1);
    int v1 = min(v0 + 1, V_N - 1);
    float w = mag * mag;
    float w00 = w * (1.0f - fv) * (1.0f - fu);
    float w01 = w * (1.0f - fv) * fu;
    float w10 = w * fv * (1.0f - fu);
    float w11 = w * fv * fu;

    int b00 = (a * V_N + v0) * U_N + u0;
    int b01 = (a * V_N + v0) * U_N + u1;
    int b10 = (a * V_N + v1) * U_N + u0;
    int b11 = (a * V_N + v1) * U_N + u1;
#pragma unroll
    for (int c = 0; c < C_N; ++c) {
      const float* pc = sino + (size_t)c * SINO_N;
      acc[c] += w00 * pc[b00] + w01 * pc[b01] + w10 * pc[b10] + w11 * pc[b11];
    }
  }

#pragma unroll
  for (int c = 0; c < C_N; ++c)
    out[(size_t)c * NVOX + vi] = acc[c];
}

extern "C" void kernel_launch(void* const* d_in, const int* in_sizes, int n_in,
                              void* d_out, int out_size, void* d_ws, size_t ws_size,
                              hipStream_t stream) {
  const float* sino   = (const float*)d_in[0];
  const float* angles = (const float*)d_in[1];
  float* out = (float*)d_out;

  size_t need = (size_t)SINO_N * sizeof(H8);   // 31.5 MB
  if (ws_size >= need) {
    H8* sino_h = (H8*)d_ws;
    sino_to_h<<<SINO_N / 256, 256, 0, stream>>>(sino, sino_h);
    backproject_u4<<<(NVOX / ZPT) / 256, 256, 0, stream>>>(sino_h, angles, out);
  } else {
    backproject_direct<<<NVOX / 256, 256, 0, stream>>>(sino, angles, out);
  }
}

// Round 11
// 219.634 us; speedup vs baseline: 1.2728x; 1.0690x over previous
//
#include <hip/hip_runtime.h>
#include <hip/hip_fp16.h>

// Cone-beam backprojection, TIGRE-style geometry.
// sinogram: [B=1, C=8, A=120, V=128, U=128] f32
// angles:   [A=120] f32
// out:      [B=1, C=8, NZ=96, NY=96, NX=96] f32
//
// v8: v5 inner loop (f16 [A][V][U][C] records, clamp-126 single-base corner
// loads, __hfma2 chunk accum, ZPT=2, fast rcp) with 2-D wave tiling:
// each wave = 8x8 (x,y) tile, block = 2x2 waves = 16x16 tile, grid (6,6,48).
// Shrinks the detector footprint per gather (u-span ~20 records, v-span 1-2
// rows -> ~6-12 cache lines/gather vs ~15-25 with 1-D x-major lanes) and the
// per-angle block patch (~2 KB) stays L1-resident across the angle loop.

#define A_N   120
#define V_N   128
#define U_N   128
#define NZv   96
#define NYv   96
#define NXv   96
#define C_N   8
#define ZPT   2                          // z per thread

constexpr float DSO  = 1000.0f;
constexpr float DSD  = 1500.0f;
constexpr float DVOX = 0.8f;

#define NVOX   (NZv * NYv * NXv)        // 884736
#define SINO_N (A_N * V_N * U_N)        // 1966080 per channel
#define CHUNK  12                        // angles per f16-accum chunk (10 flushes)

struct alignas(16) H8 { __half2 h[4]; };  // 8 channels = 16 B record

// ---------------------------------------------------------------------------
// Pre-pass: [C, A, V, U] f32 -> [A, V, U, C] f16 (one 16B record per (a,v,u))
// ---------------------------------------------------------------------------
__global__ __launch_bounds__(256) void sino_to_h(
    const float* __restrict__ in, H8* __restrict__ out) {
  int idx = blockIdx.x * 256 + threadIdx.x;   // over A*V*U, exact grid
  H8 o;
#pragma unroll
  for (int i = 0; i < 4; ++i) {
    float lo = in[(size_t)(2 * i)     * SINO_N + idx];
    float hi = in[(size_t)(2 * i + 1) * SINO_N + idx];
    o.h[i] = __floats2half2_rn(lo, hi);
  }
  out[idx] = o;
}

// ---------------------------------------------------------------------------
// Backprojection: 8x8 (x,y) wave tiles, z-pair per thread, f16 chunk accum
// ---------------------------------------------------------------------------
__global__ __launch_bounds__(256) void backproject_t8(
    const H8* __restrict__ sino,
    const float* __restrict__ angles,
    float* __restrict__ out) {
  __shared__ float s_c[A_N];
  __shared__ float s_s[A_N];
  int tid = threadIdx.x;
  if (tid < A_N) {
    float a = angles[tid];
    s_c[tid] = cosf(a);
    s_s[tid] = sinf(a);
  }
  __syncthreads();

  // wave-level 8x8 (x,y) tile; block = 2x2 waves = 16x16 tile
  int lid = tid & 63;
  int wv  = tid >> 6;                        // 0..3
  int lx  = lid & 7;
  int ly  = lid >> 3;
  int x   = blockIdx.x * 16 + (wv & 1) * 8 + lx;
  int y   = blockIdx.y * 16 + (wv >> 1) * 8 + ly;
  int z0  = blockIdx.z * ZPT;

  float xf = ((float)x - (NXv - 1) * 0.5f) * DVOX;
  float yf = ((float)y - (NYv - 1) * 0.5f) * DVOX;
  float zf[ZPT];
#pragma unroll
  for (int k = 0; k < ZPT; ++k)
    zf[k] = ((float)(z0 + k) - (NZv - 1) * 0.5f) * DVOX;

  float2  accf[ZPT][4];                       // f32 master accumulators
  __half2 acch[ZPT][4];                       // f16 chunk accumulators
#pragma unroll
  for (int k = 0; k < ZPT; ++k)
#pragma unroll
    for (int i = 0; i < 4; ++i) {
      accf[k][i] = make_float2(0.0f, 0.0f);
      acch[k][i] = __float2half2_rn(0.0f);
    }

  for (int chnk = 0; chnk < A_N / CHUNK; ++chnk) {
#pragma unroll 2
    for (int j = 0; j < CHUNK; ++j) {
      int a = chnk * CHUNK + j;
      float cs = s_c[a], sn = s_s[a];
      float xr  = xf * cs + yf * sn;
      float yr  = yf * cs - xf * sn;
      float mag = DSD * __builtin_amdgcn_rcpf(DSO - xr);  // fast rcp, ~1e-6 rel
      float w   = mag * mag;

      // u-interp setup shared by both z (clamp-126: u1 = u0+1 always)
      float iu  = yr * mag + (U_N - 1) * 0.5f;
      bool uok  = (iu >= 0.0f) && (iu <= (float)(U_N - 1));
      float iuc = fminf(fmaxf(iu, 0.0f), (float)(U_N - 1));
      float u0f = fminf(floorf(iuc), (float)(U_N - 2));
      float fu  = iuc - u0f;                  // in [0,1]
      float gu  = 1.0f - fu;
      int u0    = (int)u0f;
      float wu  = uok ? w : 0.0f;
      const H8* arow = sino + (size_t)(a * (V_N * U_N) + u0);

#pragma unroll
      for (int k = 0; k < ZPT; ++k) {
        float iv  = fmaf(zf[k], mag, (V_N - 1) * 0.5f);
        bool ok   = (iv >= 0.0f) && (iv <= (float)(V_N - 1));
        float ivc = fminf(fmaxf(iv, 0.0f), (float)(V_N - 1));
        float v0f = fminf(floorf(ivc), (float)(V_N - 2));
        float fv  = ivc - v0f;
        int v0    = (int)v0f;
        float wz  = ok ? wu : 0.0f;
        float wv0 = wz * (1.0f - fv);
        float wv1 = wz * fv;

        __half2 h00 = __float2half2_rn(wv0 * gu);
        __half2 h01 = __float2half2_rn(wv0 * fu);
        __half2 h10 = __float2half2_rn(wv1 * gu);
        __half2 h11 = __float2half2_rn(wv1 * fu);

        const H8* p = arow + v0 * U_N;        // imm offsets 0,16,2048,2064
        H8 c00 = p[0];
        H8 c01 = p[1];
        H8 c10 = p[U_N];
        H8 c11 = p[U_N + 1];

#pragma unroll
        for (int i = 0; i < 4; ++i) {
          acch[k][i] = __hfma2(c00.h[i], h00,
                       __hfma2(c01.h[i], h01,
                       __hfma2(c10.h[i], h10,
                       __hfma2(c11.h[i], h11, acch[k][i]))));
        }
      }
    }
    // flush f16 chunk into f32 master accumulators
#pragma unroll
    for (int k = 0; k < ZPT; ++k)
#pragma unroll
      for (int i = 0; i < 4; ++i) {
        float2 sf = __half22float2(acch[k][i]);
        accf[k][i].x += sf.x;
        accf[k][i].y += sf.y;
        acch[k][i] = __float2half2_rn(0.0f);
      }
  }

#pragma unroll
  for (int k = 0; k < ZPT; ++k) {
    int vi = ((z0 + k) * NYv + y) * NXv + x;
#pragma unroll
    for (int i = 0; i < 4; ++i) {
      out[(size_t)(2 * i)     * NVOX + vi] = accf[k][i].x;
      out[(size_t)(2 * i + 1) * NVOX + vi] = accf[k][i].y;
    }
  }
}

// ---------------------------------------------------------------------------
// Fallback: direct [C][A][V][U] f32 layout (if workspace too small)
// ---------------------------------------------------------------------------
__global__ __launch_bounds__(256) void backproject_direct(
    const float* __restrict__ sino,
    const float* __restrict__ angles,
    float* __restrict__ out) {
  __shared__ float s_c[A_N];
  __shared__ float s_s[A_N];
  int tid = threadIdx.x;
  if (tid < A_N) {
    float a = angles[tid];
    s_c[tid] = cosf(a);
    s_s[tid] = sinf(a);
  }
  __syncthreads();

  int vi = blockIdx.x * 256 + tid;
  int x = vi % NXv;
  int t = vi / NXv;
  int y = t % NYv;
  int z = t / NYv;

  float xf = ((float)x - (NXv - 1) * 0.5f) * DVOX;
  float yf = ((float)y - (NYv - 1) * 0.5f) * DVOX;
  float zf = ((float)z - (NZv - 1) * 0.5f) * DVOX;

  float acc[C_N];
#pragma unroll
  for (int c = 0; c < C_N; ++c) acc[c] = 0.0f;

  for (int a = 0; a < A_N; ++a) {
    float cs = s_c[a], sn = s_s[a];
    float xr = xf * cs + yf * sn;
    float yr = yf * cs - xf * sn;
    float mag = DSD / (DSO - xr);
    float iu = yr * mag + (U_N - 1) * 0.5f;
    float iv = zf * mag + (V_N - 1) * 0.5f;
    if (iu < 0.0f || iu > (float)(U_N - 1) || iv < 0.0f || iv > (float)(V_N - 1))
      continue;
    float u0f = floorf(iu), v0f = floorf(iv);
    float fu = iu - u0f, fv = iv - v0f;
    int u0 = (int)u0f, v0 = (int)v0f;
    int u1 = min(u0 + 1, U_N - 1);
    int v1 = min(v0 + 1, V_N - 1);
    float w = mag * mag;
    float w00 = w * (1.0f - fv) * (1.0f - fu);
    float w01 = w * (1.0f - fv) * fu;
    float w10 = w * fv * (1.0f - fu);
    float w11 = w * fv * fu;

    int b00 = (a * V_N + v0) * U_N + u0;
    int b01 = (a * V_N + v0) * U_N + u1;
    int b10 = (a * V_N + v1) * U_N + u0;
    int b11 = (a * V_N + v1) * U_N + u1;
#pragma unroll
    for (int c = 0; c < C_N; ++c) {
      const float* pc = sino + (size_t)c * SINO_N;
      acc[c] += w00 * pc[b00] + w01 * pc[b01] + w10 * pc[b10] + w11 * pc[b11];
    }
  }

#pragma unroll
  for (int c = 0; c < C_N; ++c)
    out[(size_t)c * NVOX + vi] = acc[c];
}

extern "C" void kernel_launch(void* const* d_in, const int* in_sizes, int n_in,
                              void* d_out, int out_size, void* d_ws, size_t ws_size,
                              hipStream_t stream) {
  const float* sino   = (const float*)d_in[0];
  const float* angles = (const float*)d_in[1];
  float* out = (float*)d_out;

  size_t need = (size_t)SINO_N * sizeof(H8);   // 31.5 MB
  if (ws_size >= need) {
    H8* sino_h = (H8*)d_ws;
    sino_to_h<<<SINO_N / 256, 256, 0, stream>>>(sino, sino_h);
    dim3 grid(NXv / 16, NYv / 16, NZv / ZPT);   // (6, 6, 48)
    backproject_t8<<<grid, 256, 0, stream>>>(sino_h, angles, out);
  } else {
    backproject_direct<<<NVOX / 256, 256, 0, stream>>>(sino, angles, out);
  }
}